// Round 2
// baseline (3314.906 us; speedup 1.0000x reference)
//
#include <hip/hip_runtime.h>
#include <hip/hip_bf16.h>

#define NB 8192
#define NT 64
#define NW 128
#define FCAP 5.0f

__device__ __forceinline__ float lrelu(float a) { return a >= 0.f ? a : 0.01f * a; }
__device__ __forceinline__ float clipc(float a) { return fminf(fmaxf(a, -FCAP), FCAP); }

// 128 WGs x 256 threads. Each WG owns 64 particles (lane p of every wave).
// Wave jg (0..3) computes hidden rows [32*jg, 32*jg+32). Hidden vectors are
// exchanged through LDS; each thread then holds the full 128-vector in regs.
// Weight addresses are wave-uniform (jg via readfirstlane) -> s_load path.
__global__ __launch_bounds__(256) void ode_kernel(
    const float* __restrict__ ts, const float* __restrict__ y0,
    const float* __restrict__ W1, const float* __restrict__ b1,
    const float* __restrict__ W2, const float* __restrict__ b2,
    const float* __restrict__ W3, const float* __restrict__ b3,
    const float* __restrict__ W4, const float* __restrict__ b4,
    float* __restrict__ out) {
  const int p = threadIdx.x & 63;
  const int jg = __builtin_amdgcn_readfirstlane((int)(threadIdx.x >> 6));
  const int gp = blockIdx.x * 64 + p;

  __shared__ float hx[64][132];  // +4 pad: keeps rows 16B-aligned, breaks pow2 stride

  float y1 = y0[2 * gp];
  float y2 = y0[2 * gp + 1];

  if (jg == 0) {
    out[2 * gp]     = clipc(y1);
    out[2 * gp + 1] = clipc(y2);
  }

  float h[NW];
  const int j0 = jg * 32;

  for (int t = 0; t < NT - 1; ++t) {
    const float dt = ts[t + 1] - ts[t];

    // ---- layer 1: h1 = lrelu(W1 @ y + b1), y is 2-wide ----
    for (int jj = 0; jj < 32; ++jj) {
      const int j = j0 + jj;
      float a = fmaf(W1[2 * j], y1, fmaf(W1[2 * j + 1], y2, b1[j]));
      hx[p][j] = lrelu(a);
    }
    __syncthreads();
#pragma unroll
    for (int k = 0; k < NW; k += 4) {
      const float4 v = *(const float4*)(&hx[p][k]);
      h[k] = v.x; h[k + 1] = v.y; h[k + 2] = v.z; h[k + 3] = v.w;
    }
    __syncthreads();

    // ---- layer 2: h2 = lrelu(W2 @ h1 + b2) ----
#pragma unroll 2
    for (int jj = 0; jj < 32; ++jj) {
      const int j = j0 + jj;
      const float* __restrict__ wr = W2 + j * NW;
      float acc = b2[j];
#pragma unroll
      for (int k = 0; k < NW; ++k) acc = fmaf(wr[k], h[k], acc);
      hx[p][j] = lrelu(acc);
    }
    __syncthreads();
#pragma unroll
    for (int k = 0; k < NW; k += 4) {
      const float4 v = *(const float4*)(&hx[p][k]);
      h[k] = v.x; h[k + 1] = v.y; h[k + 2] = v.z; h[k + 3] = v.w;
    }
    __syncthreads();

    // ---- layer 3: h3 = lrelu(W3 @ h2 + b3) ----
#pragma unroll 2
    for (int jj = 0; jj < 32; ++jj) {
      const int j = j0 + jj;
      const float* __restrict__ wr = W3 + j * NW;
      float acc = b3[j];
#pragma unroll
      for (int k = 0; k < NW; ++k) acc = fmaf(wr[k], h[k], acc);
      hx[p][j] = lrelu(acc);
    }
    __syncthreads();
#pragma unroll
    for (int k = 0; k < NW; k += 4) {
      const float4 v = *(const float4*)(&hx[p][k]);
      h[k] = v.x; h[k + 1] = v.y; h[k + 2] = v.z; h[k + 3] = v.w;
    }
    __syncthreads();

    // ---- layer 4 + Euler update (redundant across jg; only jg==0 stores) ----
    float f0 = b4[0], f1 = b4[1];
#pragma unroll
    for (int k = 0; k < NW; ++k) {
      f0 = fmaf(W4[k], h[k], f0);
      f1 = fmaf(W4[NW + k], h[k], f1);
    }
    y1 += dt * (f0 - y1);
    y2 += dt * (f1 - y2);

    if (jg == 0) {
      const int o = (t + 1) * (NB * 2) + 2 * gp;
      out[o]     = clipc(y1);
      out[o + 1] = clipc(y2);
    }
  }
}

extern "C" void kernel_launch(void* const* d_in, const int* in_sizes, int n_in,
                              void* d_out, int out_size, void* d_ws, size_t ws_size,
                              hipStream_t stream) {
  const float* ts = (const float*)d_in[0];
  const float* y0 = (const float*)d_in[1];
  const float* W1 = (const float*)d_in[2];
  const float* b1 = (const float*)d_in[3];
  const float* W2 = (const float*)d_in[4];
  const float* b2 = (const float*)d_in[5];
  const float* W3 = (const float*)d_in[6];
  const float* b3 = (const float*)d_in[7];
  const float* W4 = (const float*)d_in[8];
  const float* b4 = (const float*)d_in[9];

  ode_kernel<<<NB / 64, 256, 0, stream>>>(ts, y0, W1, b1, W2, b2, W3, b3, W4, b4,
                                          (float*)d_out);
}

// Round 3
// 86.511 us; speedup vs baseline: 38.3179x; 38.3179x over previous
//
#include <hip/hip_runtime.h>

#define NB 8192
#define NT 64
#define FCAP 5.0f

typedef unsigned int u32;
typedef float f32x16 __attribute__((ext_vector_type(16)));
typedef float f32x4 __attribute__((ext_vector_type(4)));
typedef __bf16 bf16x8 __attribute__((ext_vector_type(8)));
typedef u32 u32x4 __attribute__((ext_vector_type(4)));

static __device__ __forceinline__ u32 f2bf1(float f) {
  u32 v = __builtin_bit_cast(u32, f);
  v += 0x7fffu + ((v >> 16) & 1u);
  return v >> 16;
}
static __device__ __forceinline__ u32 pk2(float lo, float hi) {
  u32 r;
  asm("v_cvt_pk_bf16_f32 %0, %1, %2" : "=v"(r) : "v"(lo), "v"(hi));
  return r;
}
static __device__ __forceinline__ float clipc(float a) { return fminf(fmaxf(a, -FCAP), FCAP); }

// C-layout (32x32 mfma): col = lane&31, row = (reg&3) + 8*(reg>>2) + 4*(lane>>5)
// B-layout (32x32x16):   col = lane&31, k = 16*kt + 8*(lane>>5) + elem(0..7)
// For one 16-row block (C regs q..q+7): pack rows pairwise, then permlane32_swap
// exchanges lane-halves so each reg holds the B-frag k-pairs for both halves:
//   X0=pk(C0,C1) X1=pk(C2,C3) Y0=pk(C4,C5) Y1=pk(C6,C7)
//   swap(X0,Y0) -> B0=[X0.lo|Y0.lo], B2=[X0.hi|Y0.hi]; swap(X1,Y1) -> B1,B3
#define FIX8(C, q, r0, r1, r2, r3)                                        \
  {                                                                       \
    u32 X0 = pk2(C[q + 0], C[q + 1]), X1 = pk2(C[q + 2], C[q + 3]);       \
    u32 Y0 = pk2(C[q + 4], C[q + 5]), Y1 = pk2(C[q + 6], C[q + 7]);       \
    auto s0 = __builtin_amdgcn_permlane32_swap(X0, Y0, false, false);     \
    auto s1 = __builtin_amdgcn_permlane32_swap(X1, Y1, false, false);     \
    r0 = s0[0]; r1 = s1[0]; r2 = s0[1]; r3 = s1[1];                       \
  }

#define LRELU16(C)                                                        \
  _Pragma("unroll") for (int r_ = 0; r_ < 16; ++r_) {                     \
    C[r_] = fmaxf(C[r_], 0.f) + 0.01f * fminf(C[r_], 0.f);                \
  }

__global__ __launch_bounds__(256) void ode_kernel(
    const float* __restrict__ ts, const float* __restrict__ y0,
    const float* __restrict__ W1, const float* __restrict__ b1,
    const float* __restrict__ W2, const float* __restrict__ b2,
    const float* __restrict__ W3, const float* __restrict__ b3,
    const float* __restrict__ W4, const float* __restrict__ b4,
    float* __restrict__ out) {
  const int tid = threadIdx.x;
  const int w = __builtin_amdgcn_readfirstlane(tid >> 6);  // wave 0..3
  const int l = tid & 63;
  const int h = l >> 5;   // lane half
  const int c = l & 31;   // col = particle slot / A-row
  const int gp0 = blockIdx.x * 32;

  __shared__ u32 bufA[8 * 64 * 4];   // [kt][lane][4 u32] B-frag order
  __shared__ u32 bufB[8 * 64 * 4];
  __shared__ float fbuf[4 * 32 * 2]; // layer-4 partials [wave][col][2]

  // ---- state ----
  float y1 = y0[(gp0 + c) * 2];
  float y2 = y0[(gp0 + c) * 2 + 1];

  // ---- weight fragments (bf16, one-time) ----
  const int arow = 32 * w + c;  // this wave's A-operand row (out-neuron)
  bf16x8 aW2[8], aW3[8];
#pragma unroll
  for (int kt = 0; kt < 8; ++kt) {
    const float* s2 = W2 + arow * 128 + kt * 16 + 8 * h;
    f32x4 a = *(const f32x4*)s2, b = *(const f32x4*)(s2 + 4);
    u32x4 p2 = {f2bf1(a[0]) | (f2bf1(a[1]) << 16), f2bf1(a[2]) | (f2bf1(a[3]) << 16),
                f2bf1(b[0]) | (f2bf1(b[1]) << 16), f2bf1(b[2]) | (f2bf1(b[3]) << 16)};
    aW2[kt] = __builtin_bit_cast(bf16x8, p2);
    const float* s3 = W3 + arow * 128 + kt * 16 + 8 * h;
    f32x4 e = *(const f32x4*)s3, f = *(const f32x4*)(s3 + 4);
    u32x4 p3 = {f2bf1(e[0]) | (f2bf1(e[1]) << 16), f2bf1(e[2]) | (f2bf1(e[3]) << 16),
                f2bf1(f[0]) | (f2bf1(f[1]) << 16), f2bf1(f[2]) | (f2bf1(f[3]) << 16)};
    aW3[kt] = __builtin_bit_cast(bf16x8, p3);
  }
  // layer1: A = W1 (K=2 zero-padded to 16): only k=0,1 (half 0, elems 0,1)
  u32x4 p1 = {0, 0, 0, 0};
  if (h == 0) p1[0] = f2bf1(W1[arow * 2]) | (f2bf1(W1[arow * 2 + 1]) << 16);
  const bf16x8 aW1 = __builtin_bit_cast(bf16x8, p1);
  // layer4: A = W4 (M=2): rows 0,1 only; wave w covers global k in [32w,32w+32)
  u32x4 p40 = {0, 0, 0, 0}, p41 = {0, 0, 0, 0};
  if (c < 2) {
    const float* s40 = W4 + c * 128 + (2 * w) * 16 + 8 * h;
    f32x4 a = *(const f32x4*)s40, b = *(const f32x4*)(s40 + 4);
    p40 = (u32x4){f2bf1(a[0]) | (f2bf1(a[1]) << 16), f2bf1(a[2]) | (f2bf1(a[3]) << 16),
                  f2bf1(b[0]) | (f2bf1(b[1]) << 16), f2bf1(b[2]) | (f2bf1(b[3]) << 16)};
    const float* s41 = W4 + c * 128 + (2 * w + 1) * 16 + 8 * h;
    f32x4 e = *(const f32x4*)s41, f = *(const f32x4*)(s41 + 4);
    p41 = (u32x4){f2bf1(e[0]) | (f2bf1(e[1]) << 16), f2bf1(e[2]) | (f2bf1(e[3]) << 16),
                  f2bf1(f[0]) | (f2bf1(f[1]) << 16), f2bf1(f[2]) | (f2bf1(f[3]) << 16)};
  }
  const bf16x8 aW4a = __builtin_bit_cast(bf16x8, p40);
  const bf16x8 aW4b = __builtin_bit_cast(bf16x8, p41);

  // bias C-inits: row of C reg r = 32w + (r&3) + 8*(r>>2) + 4h
  float cb1[16], cb2[16], cb3[16];
#pragma unroll
  for (int r = 0; r < 16; ++r) {
    const int row = 32 * w + (r & 3) + 8 * (r >> 2) + 4 * h;
    cb1[r] = b1[row]; cb2[r] = b2[row]; cb3[r] = b3[row];
  }
  const float b40 = b4[0], b41 = b4[1];

  // t = 0 output
  if (w == 0 && h == 0) {
    float2 st = {clipc(y1), clipc(y2)};
    *(float2*)(out + (gp0 + c) * 2) = st;
  }

  for (int t = 0; t < NT - 1; ++t) {
    const float dt = ts[t + 1] - ts[t];

    // ---- layer 1: C = W1tile @ [y;0] + b1 ----
    f32x16 C;
#pragma unroll
    for (int r = 0; r < 16; ++r) C[r] = cb1[r];
    u32 yp = (h == 0) ? (f2bf1(y1) | (f2bf1(y2) << 16)) : 0u;
    u32x4 by = {yp, 0, 0, 0};
    C = __builtin_amdgcn_mfma_f32_32x32x16_bf16(aW1, __builtin_bit_cast(bf16x8, by), C, 0, 0, 0);
    LRELU16(C);
    u32 hb0, hb1, hb2, hb3, hb4, hb5, hb6, hb7;
    FIX8(C, 0, hb0, hb1, hb2, hb3);
    FIX8(C, 8, hb4, hb5, hb6, hb7);
    *(__shared__ u32x4*)&bufA[((2 * w) * 64 + l) * 4]     = (u32x4){hb0, hb1, hb2, hb3};
    *(__shared__ u32x4*)&bufA[((2 * w + 1) * 64 + l) * 4] = (u32x4){hb4, hb5, hb6, hb7};
    __syncthreads();

    // ---- layer 2: C = W2tile @ h1 + b2 ----
#pragma unroll
    for (int r = 0; r < 16; ++r) C[r] = cb2[r];
#pragma unroll
    for (int kt = 0; kt < 8; ++kt) {
      u32x4 q = *(const __shared__ u32x4*)&bufA[(kt * 64 + l) * 4];
      C = __builtin_amdgcn_mfma_f32_32x32x16_bf16(aW2[kt], __builtin_bit_cast(bf16x8, q), C, 0, 0, 0);
    }
    LRELU16(C);
    FIX8(C, 0, hb0, hb1, hb2, hb3);
    FIX8(C, 8, hb4, hb5, hb6, hb7);
    *(__shared__ u32x4*)&bufB[((2 * w) * 64 + l) * 4]     = (u32x4){hb0, hb1, hb2, hb3};
    *(__shared__ u32x4*)&bufB[((2 * w + 1) * 64 + l) * 4] = (u32x4){hb4, hb5, hb6, hb7};
    __syncthreads();

    // ---- layer 3: C = W3tile @ h2 + b3 ----
#pragma unroll
    for (int r = 0; r < 16; ++r) C[r] = cb3[r];
#pragma unroll
    for (int kt = 0; kt < 8; ++kt) {
      u32x4 q = *(const __shared__ u32x4*)&bufB[(kt * 64 + l) * 4];
      C = __builtin_amdgcn_mfma_f32_32x32x16_bf16(aW3[kt], __builtin_bit_cast(bf16x8, q), C, 0, 0, 0);
    }
    LRELU16(C);
    // own rows ARE kt=2w,2w+1 of h3 -> feed layer 4 directly from regs
    FIX8(C, 0, hb0, hb1, hb2, hb3);
    FIX8(C, 8, hb4, hb5, hb6, hb7);

    // ---- layer 4 (M=2) partial over this wave's k-range ----
    f32x16 C4;
#pragma unroll
    for (int r = 0; r < 16; ++r) C4[r] = 0.f;
    C4 = __builtin_amdgcn_mfma_f32_32x32x16_bf16(aW4a, __builtin_bit_cast(bf16x8, (u32x4){hb0, hb1, hb2, hb3}), C4, 0, 0, 0);
    C4 = __builtin_amdgcn_mfma_f32_32x32x16_bf16(aW4b, __builtin_bit_cast(bf16x8, (u32x4){hb4, hb5, hb6, hb7}), C4, 0, 0, 0);
    if (h == 0) {  // C4 reg0 = f_part[0][col], reg1 = f_part[1][col]
      fbuf[(w * 32 + c) * 2]     = C4[0];
      fbuf[(w * 32 + c) * 2 + 1] = C4[1];
    }
    __syncthreads();

    float f0 = b40, f1 = b41;
#pragma unroll
    for (int ww = 0; ww < 4; ++ww) {
      f0 += fbuf[(ww * 32 + c) * 2];
      f1 += fbuf[(ww * 32 + c) * 2 + 1];
    }
    y1 += dt * (f0 - y1);
    y2 += dt * (f1 - y2);

    if (w == 0 && h == 0) {
      float2 st = {clipc(y1), clipc(y2)};
      *(float2*)(out + (t + 1) * (NB * 2) + (gp0 + c) * 2) = st;
    }
  }
}

extern "C" void kernel_launch(void* const* d_in, const int* in_sizes, int n_in,
                              void* d_out, int out_size, void* d_ws, size_t ws_size,
                              hipStream_t stream) {
  const float* ts = (const float*)d_in[0];
  const float* y0 = (const float*)d_in[1];
  const float* W1 = (const float*)d_in[2];
  const float* b1 = (const float*)d_in[3];
  const float* W2 = (const float*)d_in[4];
  const float* b2 = (const float*)d_in[5];
  const float* W3 = (const float*)d_in[6];
  const float* b3 = (const float*)d_in[7];
  const float* W4 = (const float*)d_in[8];
  const float* b4 = (const float*)d_in[9];

  ode_kernel<<<NB / 32, 256, 0, stream>>>(ts, y0, W1, b1, W2, b2, W3, b3, W4, b4,
                                          (float*)d_out);
}